// Round 7
// baseline (389.642 us; speedup 1.0000x reference)
//
#include <hip/hip_runtime.h>

// MultiHeadAttentionBlock: B=4,S=2048,D=1024,H=16,DQ=64
// out[b,h,s,:] = diag_softmax_weight(b,h,s) * V[b,h,s,:]   (fp32 output)
//
// Split-bf16 (hi=rne, lo=rne(residual)) 3-product MFMA for the Q/K score
// path; plain bf16 for V. X split ONCE into packed MFMA fragment layout;
// projections are pure-MFMA flipped GEMMs. SCALE*log2e folded into Wq so
// attn scores are log2-domain: softmax uses exp2f + skip-far-below-max.
//
// Workspace (~113.3 MB), with aliasing:
//   Qh Ql Kh Kl Vb : 16.78 MB each; Wp_hi/lo 6.29+4.19; bits 2.10; extra 16.78
//   Xh_q=Kh, Xl_q=Kl ; Xh_k=Vb, Xl_k=extra ; Xh_v=extra  (stream-ordered)

#define BB 4
#define SS 2048
#define DD 1024
#define HH 16
#define DQQ 64

typedef unsigned short u16;
typedef unsigned int u32;
typedef __attribute__((ext_vector_type(8))) short bf16x8;
typedef __attribute__((ext_vector_type(4))) float f32x4;

static constexpr float SCALE_L2E = 0.125f * 1.44269504f;   // fold into Wq
static constexpr float NEG9 = -1e9f;
static constexpr float SKIP_T = 44.0f;                      // log2-domain skip

#define MFMA16(a, b, c) __builtin_amdgcn_mfma_f32_16x16x32_bf16((a), (b), (c), 0, 0, 0)

__device__ __forceinline__ u16 bfrne(float x) {
    u32 u = __float_as_uint(x);
    return (u16)((u + 0x7fffu + ((u >> 16) & 1u)) >> 16);
}
__device__ __forceinline__ u32 pk2(float a, float b) {
    return (u32)bfrne(a) | ((u32)bfrne(b) << 16);
}
__device__ __forceinline__ float lo_f(u32 p) { return __uint_as_float(p << 16); }
__device__ __forceinline__ float hi_f(u32 p) { return __uint_as_float(p & 0xFFFF0000u); }

union U4V { u32 u[4]; bf16x8 v; uint4 q4; };

// ---------------- mask bit-pack ----------------
__global__ __launch_bounds__(256) void mask_pack_k(const int* __restrict__ mask,
                                                   u32* __restrict__ bits) {
    const int w = blockIdx.x * 256 + threadIdx.x;            // 0 .. B*S*64-1
    const long long row  = (long long)(w >> 6);              // b*S+s
    const long long base = row * SS + (long long)((w & 63) << 5);
    const int4* mp = reinterpret_cast<const int4*>(mask + base);
    u32 v = 0;
#pragma unroll
    for (int j = 0; j < 8; ++j) {
        int4 m4 = mp[j];
        v |= (m4.x != 0 ? 1u : 0u) << (4 * j + 0);
        v |= (m4.y != 0 ? 1u : 0u) << (4 * j + 1);
        v |= (m4.z != 0 ? 1u : 0u) << (4 * j + 2);
        v |= (m4.w != 0 ? 1u : 0u) << (4 * j + 3);
    }
    bits[w] = v;
}

// ---------------- W -> packed A-fragments (hi/lo), optional pre-scale ----------------
__global__ __launch_bounds__(256) void wsplit2_k(const float* __restrict__ W,
                                                 u16* __restrict__ Ph,
                                                 u16* __restrict__ Pl,
                                                 int has_lo, float scale) {
    const int f = blockIdx.x * 4 + (threadIdx.x >> 6);       // 0..2047
    const int lane = threadIdx.x & 63;
    const int qtile = f >> 5, kc = f & 31;
    const int h = qtile >> 2, q = ((qtile & 3) << 4) + (lane & 15);
    const int d0 = kc * 32 + (lane >> 4) * 8;
    float x[8];
#pragma unroll
    for (int j = 0; j < 8; ++j)
        x[j] = W[((long long)h * DD + d0 + j) * DQQ + q] * scale;
    U4V hh;
    hh.u[0] = pk2(x[0], x[1]); hh.u[1] = pk2(x[2], x[3]);
    hh.u[2] = pk2(x[4], x[5]); hh.u[3] = pk2(x[6], x[7]);
    const long long base = ((long long)f << 9) + lane * 8;
    *reinterpret_cast<uint4*>(Ph + base) = hh.q4;
    if (has_lo) {
        U4V ll;
        ll.u[0] = pk2(x[0] - lo_f(hh.u[0]), x[1] - hi_f(hh.u[0]));
        ll.u[1] = pk2(x[2] - lo_f(hh.u[1]), x[3] - hi_f(hh.u[1]));
        ll.u[2] = pk2(x[4] - lo_f(hh.u[2]), x[5] - hi_f(hh.u[2]));
        ll.u[3] = pk2(x[6] - lo_f(hh.u[3]), x[7] - hi_f(hh.u[3]));
        *reinterpret_cast<uint4*>(Pl + base) = ll.q4;
    }
}

// ---------------- X -> packed B-fragments (hi[/lo]), one pass ----------------
__global__ __launch_bounds__(256) void splitx_k(const float* __restrict__ X,
                                                u16* __restrict__ Xh,
                                                u16* __restrict__ Xl,
                                                int has_lo) {
    const int g = blockIdx.x * 256 + threadIdx.x;   // 0 .. 8192*32-1
    const int kc = g & 31;
    const int row = g >> 5;
    const float* xp = X + ((long long)row << 10) + kc * 32;
    const int lrow = row & 15;
    const long long base = (((long long)(row >> 4) * 32 + kc) << 9);
    float4 f[8];
#pragma unroll
    for (int i = 0; i < 8; ++i) f[i] = reinterpret_cast<const float4*>(xp)[i];
#pragma unroll
    for (int lg = 0; lg < 4; ++lg) {
        const float v0 = f[2 * lg].x, v1 = f[2 * lg].y, v2 = f[2 * lg].z, v3 = f[2 * lg].w;
        const float v4 = f[2 * lg + 1].x, v5 = f[2 * lg + 1].y,
                    v6 = f[2 * lg + 1].z, v7 = f[2 * lg + 1].w;
        U4V hh;
        hh.u[0] = pk2(v0, v1); hh.u[1] = pk2(v2, v3);
        hh.u[2] = pk2(v4, v5); hh.u[3] = pk2(v6, v7);
        const long long o = base + (lrow + 16 * lg) * 8;
        *reinterpret_cast<uint4*>(Xh + o) = hh.q4;
        if (has_lo) {
            U4V ll;
            ll.u[0] = pk2(v0 - lo_f(hh.u[0]), v1 - hi_f(hh.u[0]));
            ll.u[1] = pk2(v2 - lo_f(hh.u[1]), v3 - hi_f(hh.u[1]));
            ll.u[2] = pk2(v4 - lo_f(hh.u[2]), v5 - hi_f(hh.u[2]));
            ll.u[3] = pk2(v6 - lo_f(hh.u[3]), v7 - hi_f(hh.u[3]));
            *reinterpret_cast<uint4*>(Xl + o) = ll.q4;
        }
    }
}

// ---------------- Q/K projection (pure MFMA, packed operands) ----------------
__global__ __launch_bounds__(256) void proj_qk2_k(
        const u16* __restrict__ Xh, const u16* __restrict__ Xl,
        const u16* __restrict__ Wph, const u16* __restrict__ Wpl,
        u16* __restrict__ Oh, u16* __restrict__ Ol) {
    const int t = threadIdx.x, lane = t & 63, wid = t >> 6;
    const int lrow = lane & 15, lgrp = lane >> 4;
    const int qt0 = blockIdx.y * 8 + (wid >> 1) * 4;
    const int st0 = blockIdx.x * 8 + (wid & 1) * 4;

    f32x4 acc[4][4];
#pragma unroll
    for (int i = 0; i < 4; ++i)
#pragma unroll
        for (int j = 0; j < 4; ++j) acc[i][j] = (f32x4){0.f, 0.f, 0.f, 0.f};

#pragma unroll 2
    for (int kc = 0; kc < 32; ++kc) {
        bf16x8 Ah[4], Al[4], Bh[4], Bl[4];
#pragma unroll
        for (int mt = 0; mt < 4; ++mt) {
            const long long ab = (((long long)(qt0 + mt) * 32 + kc) << 9) + lane * 8;
            Ah[mt] = *reinterpret_cast<const bf16x8*>(Wph + ab);
            Al[mt] = *reinterpret_cast<const bf16x8*>(Wpl + ab);
        }
#pragma unroll
        for (int nt = 0; nt < 4; ++nt) {
            const long long bb = (((long long)(st0 + nt) * 32 + kc) << 9) + lane * 8;
            Bh[nt] = *reinterpret_cast<const bf16x8*>(Xh + bb);
            Bl[nt] = *reinterpret_cast<const bf16x8*>(Xl + bb);
        }
#pragma unroll
        for (int mt = 0; mt < 4; ++mt)
#pragma unroll
            for (int nt = 0; nt < 4; ++nt) {
                acc[mt][nt] = MFMA16(Ah[mt], Bh[nt], acc[mt][nt]);
                acc[mt][nt] = MFMA16(Ah[mt], Bl[nt], acc[mt][nt]);
                acc[mt][nt] = MFMA16(Al[mt], Bh[nt], acc[mt][nt]);
            }
    }

    // epilogue: 8B contiguous stores into packed fragment layout (HW-verified)
#pragma unroll
    for (int mt = 0; mt < 4; ++mt) {
        const int qtg = qt0 + mt;
        const int hh_ = qtg >> 2;
        const int qb = ((qtg & 3) << 4) + (lgrp << 2);     // q of r=0
#pragma unroll
        for (int nt = 0; nt < 4; ++nt) {
            const int c = (st0 + nt) * 16 + lrow;
            const int b = c >> 11, s = c & 2047;
            const int bh = (b << 4) + hh_;
            const float x0 = acc[mt][nt][0], x1 = acc[mt][nt][1],
                        x2 = acc[mt][nt][2], x3 = acc[mt][nt][3];
            const u32 h01 = pk2(x0, x1), h23 = pk2(x2, x3);
            const u32 l01 = pk2(x0 - lo_f(h01), x1 - hi_f(h01));
            const u32 l23 = pk2(x2 - lo_f(h23), x3 - hi_f(h23));
            const int st = s >> 4, kcq = qb >> 5;
            const int lanep = lrow + (((qb & 31) >> 3) << 4);
            const long long oi = ((((long long)bh * 128 + st) * 2 + kcq) << 9)
                                 + lanep * 8 + (qb & 7);
            *reinterpret_cast<uint2*>(Oh + oi) = make_uint2(h01, h23);
            *reinterpret_cast<uint2*>(Ol + oi) = make_uint2(l01, l23);
        }
    }
}

// ---------------- V projection (pure MFMA, bf16, row-major out) ----------------
__global__ __launch_bounds__(256) void proj_v2_k(
        const u16* __restrict__ Xh, const u16* __restrict__ Wph,
        u16* __restrict__ Vb) {
    const int t = threadIdx.x, lane = t & 63, wid = t >> 6;
    const int lrow = lane & 15, lgrp = lane >> 4;
    const int qt0 = blockIdx.y * 8 + (wid >> 1) * 4;
    const int st0 = blockIdx.x * 8 + (wid & 1) * 4;

    f32x4 acc[4][4];
#pragma unroll
    for (int i = 0; i < 4; ++i)
#pragma unroll
        for (int j = 0; j < 4; ++j) acc[i][j] = (f32x4){0.f, 0.f, 0.f, 0.f};

#pragma unroll 2
    for (int kc = 0; kc < 32; ++kc) {
        bf16x8 Ah[4], Bh[4];
#pragma unroll
        for (int mt = 0; mt < 4; ++mt) {
            const long long ab = (((long long)(qt0 + mt) * 32 + kc) << 9) + lane * 8;
            Ah[mt] = *reinterpret_cast<const bf16x8*>(Wph + ab);
        }
#pragma unroll
        for (int nt = 0; nt < 4; ++nt) {
            const long long bb = (((long long)(st0 + nt) * 32 + kc) << 9) + lane * 8;
            Bh[nt] = *reinterpret_cast<const bf16x8*>(Xh + bb);
        }
#pragma unroll
        for (int mt = 0; mt < 4; ++mt)
#pragma unroll
            for (int nt = 0; nt < 4; ++nt)
                acc[mt][nt] = MFMA16(Ah[mt], Bh[nt], acc[mt][nt]);
    }

#pragma unroll
    for (int mt = 0; mt < 4; ++mt) {
        const int qtg = qt0 + mt;
        const int hh_ = qtg >> 2;
        const int qb = ((qtg & 3) << 4) + (lgrp << 2);
#pragma unroll
        for (int nt = 0; nt < 4; ++nt) {
            const int c = (st0 + nt) * 16 + lrow;
            const int b = c >> 11, s = c & 2047;
            const int bh = (b << 4) + hh_;
            const u32 h01 = pk2(acc[mt][nt][0], acc[mt][nt][1]);
            const u32 h23 = pk2(acc[mt][nt][2], acc[mt][nt][3]);
            const long long oi = ((long long)bh * SS + s) * DQQ + qb;
            *reinterpret_cast<uint2*>(Vb + oi) = make_uint2(h01, h23);
        }
    }
}

// ---------------- fused scores + online softmax diag + output ----------------
// Scores are log2-domain (SCALE*log2e folded into Wq). exp2f + skip branch.
__global__ __launch_bounds__(256) void attn_k(
        const u16* __restrict__ Qh, const u16* __restrict__ Ql,
        const u16* __restrict__ Kh, const u16* __restrict__ Kl,
        const u16* __restrict__ Vb, const u32* __restrict__ bits,
        float* __restrict__ out) {
    const int qt = blockIdx.x, h = blockIdx.y, b = blockIdx.z;
    const int s0 = qt * 128;
    const long long bh = b * HH + h;
    const int t = threadIdx.x, lane = t & 63, wid = t >> 6;

    __shared__ u16 Kst[2][2][4096];
    __shared__ float sdiag[128];
    __shared__ float dwgt[128];

    bf16x8 qfh[2][2], qfl[2][2];
#pragma unroll
    for (int mt = 0; mt < 2; ++mt)
#pragma unroll
        for (int ks = 0; ks < 2; ++ks) {
            const int stq = qt * 8 + wid * 2 + mt;
            const long long gi = (((bh * 128 + stq) * 2 + ks) << 9) + lane * 8;
            qfh[mt][ks] = *reinterpret_cast<const bf16x8*>(&Qh[gi]);
            qfl[mt][ks] = *reinterpret_cast<const bf16x8*>(&Ql[gi]);
        }

    bf16x8 sh[2], sl[2];
    auto loadK = [&](int cchN) {
        const long long base = (bh * 128 + cchN * 4) * 1024;
#pragma unroll
        for (int i = 0; i < 2; ++i) {
            const long long so = base + (long long)(t + i * 256) * 8;
            sh[i] = *reinterpret_cast<const bf16x8*>(&Kh[so]);
            sl[i] = *reinterpret_cast<const bf16x8*>(&Kl[so]);
        }
    };
    auto stageK = [&](int buf) {
#pragma unroll
        for (int i = 0; i < 2; ++i) {
            *reinterpret_cast<bf16x8*>(&Kst[buf][0][(t + i * 256) * 8]) = sh[i];
            *reinterpret_cast<bf16x8*>(&Kst[buf][1][(t + i * 256) * 8]) = sl[i];
        }
    };

    loadK(0);
    stageK(0);

    float mrun[2][4], srun[2][4];
#pragma unroll
    for (int mt = 0; mt < 2; ++mt)
#pragma unroll
        for (int r = 0; r < 4; ++r) { mrun[mt][r] = -INFINITY; srun[mt][r] = 0.f; }

    const int cc0 = s0 >> 6;

    for (int cch = 0; cch < 32; ++cch) {
        const int cur = cch & 1;
        const int t0 = cch * 64;
        __syncthreads();
        if (cch + 1 < 32) loadK(cch + 1);

        u32 mw0[2][4], mw1[2][4];
#pragma unroll
        for (int mt = 0; mt < 2; ++mt)
#pragma unroll
            for (int r = 0; r < 4; ++r) {
                long long mi = ((long long)(b * SS) + s0 + wid * 32 + mt * 16 + (lane >> 4) * 4 + r) * 64 + cch * 2;
                mw0[mt][r] = bits[mi];
                mw1[mt][r] = bits[mi + 1];
            }

        bf16x8 kfh[4][2], kfl[4][2];
#pragma unroll
        for (int nt = 0; nt < 4; ++nt)
#pragma unroll
            for (int ks = 0; ks < 2; ++ks) {
                kfh[nt][ks] = *reinterpret_cast<const bf16x8*>(&Kst[cur][0][(nt * 2 + ks) * 512 + lane * 8]);
                kfl[nt][ks] = *reinterpret_cast<const bf16x8*>(&Kst[cur][1][(nt * 2 + ks) * 512 + lane * 8]);
            }

        f32x4 sc[2][4];
        const f32x4 zz = (f32x4){0.f, 0.f, 0.f, 0.f};
#pragma unroll
        for (int mt = 0; mt < 2; ++mt)
#pragma unroll
            for (int nt = 0; nt < 4; ++nt) {
                f32x4 a = MFMA16(qfh[mt][0], kfh[nt][0], zz);
                a = MFMA16(qfh[mt][1], kfh[nt][1], a);
                a = MFMA16(qfh[mt][0], kfl[nt][0], a);
                a = MFMA16(qfh[mt][1], kfl[nt][1], a);
                a = MFMA16(qfl[mt][0], kfh[nt][0], a);
                a = MFMA16(qfl[mt][1], kfh[nt][1], a);
                sc[mt][nt] = a;
            }

        const bool dchunk = (cch == cc0) || (cch == cc0 + 1);
#pragma unroll
        for (int mt = 0; mt < 2; ++mt)
#pragma unroll
            for (int r = 0; r < 4; ++r) {
                float v[4];
                u32 w0 = mw0[mt][r], w1 = mw1[mt][r];
#pragma unroll
                for (int nt = 0; nt < 4; ++nt) {
                    u32 w = (nt < 2) ? w0 : w1;
                    u32 bit = (w >> ((nt & 1) * 16 + (lane & 15))) & 1u;
                    v[nt] = bit ? sc[mt][nt][r] : NEG9;       // log2-domain
                }
                if (dchunk) {
                    int sl_ = wid * 32 + mt * 16 + (lane >> 4) * 4 + r;
                    int cd = s0 + sl_ - t0;
#pragma unroll
                    for (int nt = 0; nt < 4; ++nt)
                        if (cd >= 0 && cd < 64 && (cd >> 4) == nt && (cd & 15) == (lane & 15))
                            sdiag[sl_] = v[nt];
                }
                float vmax = fmaxf(fmaxf(v[0], v[1]), fmaxf(v[2], v[3]));
                float mo = mrun[mt][r];
                if (vmax > mo - SKIP_T) {                     // contribution >= 2^-44
                    float mn = fmaxf(mo, vmax);
                    float ssum = exp2f(v[0] - mn) + exp2f(v[1] - mn) +
                                 exp2f(v[2] - mn) + exp2f(v[3] - mn);
                    srun[mt][r] = srun[mt][r] * exp2f(mo - mn) + ssum;
                    mrun[mt][r] = mn;
                }
            }

        if (cch + 1 < 32) stageK(cur ^ 1);
    }

#pragma unroll
    for (int mt = 0; mt < 2; ++mt)
#pragma unroll
        for (int r = 0; r < 4; ++r) {
            float mo = mrun[mt][r], so = srun[mt][r];
#pragma unroll
            for (int st = 1; st < 16; st <<= 1) {
                float m2 = __shfl_xor(mo, st, 64);
                float s2 = __shfl_xor(so, st, 64);
                float mn = fmaxf(mo, m2);
                so = so * exp2f(mo - mn) + s2 * exp2f(m2 - mn);
                mo = mn;
            }
            if ((lane & 15) == 0) {
                int sl_ = wid * 32 + mt * 16 + (lane >> 4) * 4 + r;
                dwgt[sl_] = exp2f(sdiag[sl_] - mo) / so;
            }
        }
    __syncthreads();

    const int orow = t >> 1, oc = (t & 1) * 32;
    const float w = dwgt[orow];
    const u16* vp = Vb + (bh * SS + s0 + orow) * DQQ + oc;
    float* op = out + (bh * SS + s0 + orow) * DQQ + oc;
#pragma unroll
    for (int j = 0; j < 8; ++j) {
        u32 pv = *reinterpret_cast<const u32*>(&vp[j * 4 + 0]);
        u32 pv2 = *reinterpret_cast<const u32*>(&vp[j * 4 + 2]);
        float4 o;
        o.x = lo_f(pv) * w;  o.y = hi_f(pv) * w;
        o.z = lo_f(pv2) * w; o.w = hi_f(pv2) * w;
        reinterpret_cast<float4*>(op)[j] = o;
    }
}

extern "C" void kernel_launch(void* const* d_in, const int* in_sizes, int n_in,
                              void* d_out, int out_size, void* d_ws, size_t ws_size,
                              hipStream_t stream) {
    (void)in_sizes; (void)n_in; (void)out_size; (void)ws_size;
    const float* q    = (const float*)d_in[0];
    const float* k    = (const float*)d_in[1];
    const float* v    = (const float*)d_in[2];
    const int*   mask = (const int*)d_in[3];
    const float* wq   = (const float*)d_in[4];
    const float* wk   = (const float*)d_in[5];
    const float* wv   = (const float*)d_in[6];

    const size_t NP2 = (size_t)BB * HH * SS * DQQ * 2;   // 16.78 MB per unit
    char* wsp = (char*)d_ws;
    u16* Qh = (u16*)wsp;            wsp += NP2;
    u16* Ql = (u16*)wsp;            wsp += NP2;
    u16* Kh = (u16*)wsp;            wsp += NP2;
    u16* Kl = (u16*)wsp;            wsp += NP2;
    u16* Vb = (u16*)wsp;            wsp += NP2;
    u16* Wph = (u16*)wsp;           wsp += (size_t)3 * 2048 * 512 * 2;
    u16* Wpl = (u16*)wsp;           wsp += (size_t)2 * 2048 * 512 * 2;
    u32* bits = (u32*)wsp;          wsp += (size_t)BB * SS * 64 * 4;
    u16* extra = (u16*)wsp;         // 16.78 MB slab

    // Aliased X-fragment slabs (stream-ordered hazards only)
    u16* Xh_q = Kh;    u16* Xl_q = Kl;
    u16* Xh_k = Vb;    u16* Xl_k = extra;
    u16* Xh_v = extra;

    mask_pack_k<<<dim3(2048), dim3(256), 0, stream>>>(mask, bits);
    wsplit2_k<<<dim3(512), dim3(256), 0, stream>>>(wq, Wph, Wpl, 1, SCALE_L2E);
    wsplit2_k<<<dim3(512), dim3(256), 0, stream>>>(wk, Wph + (1 << 20), Wpl + (1 << 20), 1, 1.0f);
    wsplit2_k<<<dim3(512), dim3(256), 0, stream>>>(wv, Wph + (2u << 20), Wph, 0, 1.0f);

    splitx_k<<<dim3(1024), dim3(256), 0, stream>>>(q, Xh_q, Xl_q, 1);
    proj_qk2_k<<<dim3(64, 8), dim3(256), 0, stream>>>(Xh_q, Xl_q, Wph, Wpl, Qh, Ql);

    splitx_k<<<dim3(1024), dim3(256), 0, stream>>>(k, Xh_k, Xl_k, 1);
    proj_qk2_k<<<dim3(64, 8), dim3(256), 0, stream>>>(Xh_k, Xl_k,
                                                      Wph + (1 << 20), Wpl + (1 << 20),
                                                      Kh, Kl);

    splitx_k<<<dim3(1024), dim3(256), 0, stream>>>(v, Xh_v, Xh_v, 0);
    proj_v2_k<<<dim3(64, 8), dim3(256), 0, stream>>>(Xh_v, Wph + (2u << 20), Vb);

    attn_k<<<dim3(16, 16, 4), dim3(256), 0, stream>>>(Qh, Ql, Kh, Kl, Vb, bits,
                                                      (float*)d_out);
}

// Round 8
// 388.797 us; speedup vs baseline: 1.0022x; 1.0022x over previous
//
#include <hip/hip_runtime.h>

// MultiHeadAttentionBlock: B=4,S=2048,D=1024,H=16,DQ=64
// out[b,h,s,:] = diag_softmax_weight(b,h,s) * V[b,h,s,:]   (fp32 output)
//
// Split-bf16 (hi=rne, lo=rne(residual)) 3-product MFMA for the Q/K score
// path; plain bf16 for V. X split ONCE into packed MFMA fragment layout;
// projections are pure-MFMA flipped GEMMs. SCALE*log2e folded into Wq so
// attn scores are log2-domain (exp2, no per-score scale). Softmax update is
// UNCONDITIONAL (r7's divergent skip-branch regressed). All per-chunk attn
// addressing is hoisted to u32 increments (no 64-bit mads in the hot loop).
//
// Workspace (~113.3 MB), with aliasing:
//   Qh Ql Kh Kl Vb : 16.78 MB each; Wp_hi/lo 6.29+4.19; bits 2.10; extra 16.78
//   Xh_q=Kh, Xl_q=Kl ; Xh_k=Vb, Xl_k=extra ; Xh_v=extra  (stream-ordered)

#define BB 4
#define SS 2048
#define DD 1024
#define HH 16
#define DQQ 64

typedef unsigned short u16;
typedef unsigned int u32;
typedef __attribute__((ext_vector_type(8))) short bf16x8;
typedef __attribute__((ext_vector_type(4))) float f32x4;

static constexpr float SCALE_L2E = 0.125f * 1.44269504f;   // folded into Wq
static constexpr float NEG9 = -1e9f;

#define MFMA16(a, b, c) __builtin_amdgcn_mfma_f32_16x16x32_bf16((a), (b), (c), 0, 0, 0)

__device__ __forceinline__ u16 bfrne(float x) {
    u32 u = __float_as_uint(x);
    return (u16)((u + 0x7fffu + ((u >> 16) & 1u)) >> 16);
}
__device__ __forceinline__ u32 pk2(float a, float b) {
    return (u32)bfrne(a) | ((u32)bfrne(b) << 16);
}
__device__ __forceinline__ float lo_f(u32 p) { return __uint_as_float(p << 16); }
__device__ __forceinline__ float hi_f(u32 p) { return __uint_as_float(p & 0xFFFF0000u); }

union U4V { u32 u[4]; bf16x8 v; uint4 q4; };

// ---------------- mask bit-pack ----------------
__global__ __launch_bounds__(256) void mask_pack_k(const int* __restrict__ mask,
                                                   u32* __restrict__ bits) {
    const int w = blockIdx.x * 256 + threadIdx.x;            // 0 .. B*S*64-1
    const long long row  = (long long)(w >> 6);              // b*S+s
    const long long base = row * SS + (long long)((w & 63) << 5);
    const int4* mp = reinterpret_cast<const int4*>(mask + base);
    u32 v = 0;
#pragma unroll
    for (int j = 0; j < 8; ++j) {
        int4 m4 = mp[j];
        v |= (m4.x != 0 ? 1u : 0u) << (4 * j + 0);
        v |= (m4.y != 0 ? 1u : 0u) << (4 * j + 1);
        v |= (m4.z != 0 ? 1u : 0u) << (4 * j + 2);
        v |= (m4.w != 0 ? 1u : 0u) << (4 * j + 3);
    }
    bits[w] = v;
}

// ---------------- W -> packed A-fragments (hi/lo), optional pre-scale ----------------
__global__ __launch_bounds__(256) void wsplit2_k(const float* __restrict__ W,
                                                 u16* __restrict__ Ph,
                                                 u16* __restrict__ Pl,
                                                 int has_lo, float scale) {
    const int f = blockIdx.x * 4 + (threadIdx.x >> 6);       // 0..2047
    const int lane = threadIdx.x & 63;
    const int qtile = f >> 5, kc = f & 31;
    const int h = qtile >> 2, q = ((qtile & 3) << 4) + (lane & 15);
    const int d0 = kc * 32 + (lane >> 4) * 8;
    float x[8];
#pragma unroll
    for (int j = 0; j < 8; ++j)
        x[j] = W[((long long)h * DD + d0 + j) * DQQ + q] * scale;
    U4V hh;
    hh.u[0] = pk2(x[0], x[1]); hh.u[1] = pk2(x[2], x[3]);
    hh.u[2] = pk2(x[4], x[5]); hh.u[3] = pk2(x[6], x[7]);
    const long long base = ((long long)f << 9) + lane * 8;
    *reinterpret_cast<uint4*>(Ph + base) = hh.q4;
    if (has_lo) {
        U4V ll;
        ll.u[0] = pk2(x[0] - lo_f(hh.u[0]), x[1] - hi_f(hh.u[0]));
        ll.u[1] = pk2(x[2] - lo_f(hh.u[1]), x[3] - hi_f(hh.u[1]));
        ll.u[2] = pk2(x[4] - lo_f(hh.u[2]), x[5] - hi_f(hh.u[2]));
        ll.u[3] = pk2(x[6] - lo_f(hh.u[3]), x[7] - hi_f(hh.u[3]));
        *reinterpret_cast<uint4*>(Pl + base) = ll.q4;
    }
}

// ---------------- X -> packed B-fragments (hi[/lo]), one pass ----------------
__global__ __launch_bounds__(256) void splitx_k(const float* __restrict__ X,
                                                u16* __restrict__ Xh,
                                                u16* __restrict__ Xl,
                                                int has_lo) {
    const int g = blockIdx.x * 256 + threadIdx.x;   // 0 .. 8192*32-1
    const int kc = g & 31;
    const int row = g >> 5;
    const float* xp = X + ((long long)row << 10) + kc * 32;
    const int lrow = row & 15;
    const long long base = (((long long)(row >> 4) * 32 + kc) << 9);
    float4 f[8];
#pragma unroll
    for (int i = 0; i < 8; ++i) f[i] = reinterpret_cast<const float4*>(xp)[i];
#pragma unroll
    for (int lg = 0; lg < 4; ++lg) {
        const float v0 = f[2 * lg].x, v1 = f[2 * lg].y, v2 = f[2 * lg].z, v3 = f[2 * lg].w;
        const float v4 = f[2 * lg + 1].x, v5 = f[2 * lg + 1].y,
                    v6 = f[2 * lg + 1].z, v7 = f[2 * lg + 1].w;
        U4V hh;
        hh.u[0] = pk2(v0, v1); hh.u[1] = pk2(v2, v3);
        hh.u[2] = pk2(v4, v5); hh.u[3] = pk2(v6, v7);
        const long long o = base + (lrow + 16 * lg) * 8;
        *reinterpret_cast<uint4*>(Xh + o) = hh.q4;
        if (has_lo) {
            U4V ll;
            ll.u[0] = pk2(v0 - lo_f(hh.u[0]), v1 - hi_f(hh.u[0]));
            ll.u[1] = pk2(v2 - lo_f(hh.u[1]), v3 - hi_f(hh.u[1]));
            ll.u[2] = pk2(v4 - lo_f(hh.u[2]), v5 - hi_f(hh.u[2]));
            ll.u[3] = pk2(v6 - lo_f(hh.u[3]), v7 - hi_f(hh.u[3]));
            *reinterpret_cast<uint4*>(Xl + o) = ll.q4;
        }
    }
}

// ---------------- Q/K projection (pure MFMA, packed operands) ----------------
__global__ __launch_bounds__(256) void proj_qk2_k(
        const u16* __restrict__ Xh, const u16* __restrict__ Xl,
        const u16* __restrict__ Wph, const u16* __restrict__ Wpl,
        u16* __restrict__ Oh, u16* __restrict__ Ol) {
    const int t = threadIdx.x, lane = t & 63, wid = t >> 6;
    const int lrow = lane & 15, lgrp = lane >> 4;
    const int qt0 = blockIdx.y * 8 + (wid >> 1) * 4;
    const int st0 = blockIdx.x * 8 + (wid & 1) * 4;

    f32x4 acc[4][4];
#pragma unroll
    for (int i = 0; i < 4; ++i)
#pragma unroll
        for (int j = 0; j < 4; ++j) acc[i][j] = (f32x4){0.f, 0.f, 0.f, 0.f};

#pragma unroll 2
    for (int kc = 0; kc < 32; ++kc) {
        bf16x8 Ah[4], Al[4], Bh[4], Bl[4];
#pragma unroll
        for (int mt = 0; mt < 4; ++mt) {
            const long long ab = (((long long)(qt0 + mt) * 32 + kc) << 9) + lane * 8;
            Ah[mt] = *reinterpret_cast<const bf16x8*>(Wph + ab);
            Al[mt] = *reinterpret_cast<const bf16x8*>(Wpl + ab);
        }
#pragma unroll
        for (int nt = 0; nt < 4; ++nt) {
            const long long bb = (((long long)(st0 + nt) * 32 + kc) << 9) + lane * 8;
            Bh[nt] = *reinterpret_cast<const bf16x8*>(Xh + bb);
            Bl[nt] = *reinterpret_cast<const bf16x8*>(Xl + bb);
        }
#pragma unroll
        for (int mt = 0; mt < 4; ++mt)
#pragma unroll
            for (int nt = 0; nt < 4; ++nt) {
                acc[mt][nt] = MFMA16(Ah[mt], Bh[nt], acc[mt][nt]);
                acc[mt][nt] = MFMA16(Ah[mt], Bl[nt], acc[mt][nt]);
                acc[mt][nt] = MFMA16(Al[mt], Bh[nt], acc[mt][nt]);
            }
    }

    // epilogue: 8B contiguous stores into packed fragment layout (HW-verified)
#pragma unroll
    for (int mt = 0; mt < 4; ++mt) {
        const int qtg = qt0 + mt;
        const int hh_ = qtg >> 2;
        const int qb = ((qtg & 3) << 4) + (lgrp << 2);     // q of r=0
#pragma unroll
        for (int nt = 0; nt < 4; ++nt) {
            const int c = (st0 + nt) * 16 + lrow;
            const int b = c >> 11, s = c & 2047;
            const int bh = (b << 4) + hh_;
            const float x0 = acc[mt][nt][0], x1 = acc[mt][nt][1],
                        x2 = acc[mt][nt][2], x3 = acc[mt][nt][3];
            const u32 h01 = pk2(x0, x1), h23 = pk2(x2, x3);
            const u32 l01 = pk2(x0 - lo_f(h01), x1 - hi_f(h01));
            const u32 l23 = pk2(x2 - lo_f(h23), x3 - hi_f(h23));
            const int st = s >> 4, kcq = qb >> 5;
            const int lanep = lrow + (((qb & 31) >> 3) << 4);
            const long long oi = ((((long long)bh * 128 + st) * 2 + kcq) << 9)
                                 + lanep * 8 + (qb & 7);
            *reinterpret_cast<uint2*>(Oh + oi) = make_uint2(h01, h23);
            *reinterpret_cast<uint2*>(Ol + oi) = make_uint2(l01, l23);
        }
    }
}

// ---------------- V projection (pure MFMA, bf16, row-major out) ----------------
__global__ __launch_bounds__(256) void proj_v2_k(
        const u16* __restrict__ Xh, const u16* __restrict__ Wph,
        u16* __restrict__ Vb) {
    const int t = threadIdx.x, lane = t & 63, wid = t >> 6;
    const int lrow = lane & 15, lgrp = lane >> 4;
    const int qt0 = blockIdx.y * 8 + (wid >> 1) * 4;
    const int st0 = blockIdx.x * 8 + (wid & 1) * 4;

    f32x4 acc[4][4];
#pragma unroll
    for (int i = 0; i < 4; ++i)
#pragma unroll
        for (int j = 0; j < 4; ++j) acc[i][j] = (f32x4){0.f, 0.f, 0.f, 0.f};

#pragma unroll 2
    for (int kc = 0; kc < 32; ++kc) {
        bf16x8 Ah[4], Bh[4];
#pragma unroll
        for (int mt = 0; mt < 4; ++mt) {
            const long long ab = (((long long)(qt0 + mt) * 32 + kc) << 9) + lane * 8;
            Ah[mt] = *reinterpret_cast<const bf16x8*>(Wph + ab);
        }
#pragma unroll
        for (int nt = 0; nt < 4; ++nt) {
            const long long bb = (((long long)(st0 + nt) * 32 + kc) << 9) + lane * 8;
            Bh[nt] = *reinterpret_cast<const bf16x8*>(Xh + bb);
        }
#pragma unroll
        for (int mt = 0; mt < 4; ++mt)
#pragma unroll
            for (int nt = 0; nt < 4; ++nt)
                acc[mt][nt] = MFMA16(Ah[mt], Bh[nt], acc[mt][nt]);
    }

#pragma unroll
    for (int mt = 0; mt < 4; ++mt) {
        const int qtg = qt0 + mt;
        const int hh_ = qtg >> 2;
        const int qb = ((qtg & 3) << 4) + (lgrp << 2);
#pragma unroll
        for (int nt = 0; nt < 4; ++nt) {
            const int c = (st0 + nt) * 16 + lrow;
            const int b = c >> 11, s = c & 2047;
            const int bh = (b << 4) + hh_;
            const u32 h01 = pk2(acc[mt][nt][0], acc[mt][nt][1]);
            const u32 h23 = pk2(acc[mt][nt][2], acc[mt][nt][3]);
            const long long oi = ((long long)bh * SS + s) * DQQ + qb;
            *reinterpret_cast<uint2*>(Vb + oi) = make_uint2(h01, h23);
        }
    }
}

// ---------------- fused scores + online softmax diag + output ----------------
// Scores log2-domain. Unconditional online update; all hot-loop addressing
// is u32 offsets off uniform bases (no 64-bit mads per chunk).
__global__ __launch_bounds__(256) void attn_k(
        const u16* __restrict__ Qh, const u16* __restrict__ Ql,
        const u16* __restrict__ Kh, const u16* __restrict__ Kl,
        const u16* __restrict__ Vb, const u32* __restrict__ bits,
        float* __restrict__ out) {
    const int qt = blockIdx.x, h = blockIdx.y, b = blockIdx.z;
    const int s0 = qt * 128;
    const long long bh = b * HH + h;
    const int t = threadIdx.x, lane = t & 63, wid = t >> 6;
    const int l15 = lane & 15;

    __shared__ u16 Kst[2][2][4096];
    __shared__ float sdiag[128];
    __shared__ float dwgt[128];

    bf16x8 qfh[2][2], qfl[2][2];
#pragma unroll
    for (int mt = 0; mt < 2; ++mt)
#pragma unroll
        for (int ks = 0; ks < 2; ++ks) {
            const int stq = qt * 8 + wid * 2 + mt;
            const long long gi = (((bh * 128 + stq) * 2 + ks) << 9) + lane * 8;
            qfh[mt][ks] = *reinterpret_cast<const bf16x8*>(&Qh[gi]);
            qfl[mt][ks] = *reinterpret_cast<const bf16x8*>(&Ql[gi]);
        }

    // K staging: u32 element offsets off uniform bases (chunk adds 4096)
    const u32 kbase = (u32)(bh * 131072u) + (u32)t * 8u;
    bf16x8 sh[2], sl[2];
    auto loadK = [&](int cchN) {
        const u32 o = kbase + (u32)cchN * 4096u;
        sh[0] = *reinterpret_cast<const bf16x8*>(Kh + o);
        sl[0] = *reinterpret_cast<const bf16x8*>(Kl + o);
        sh[1] = *reinterpret_cast<const bf16x8*>(Kh + o + 2048u);
        sl[1] = *reinterpret_cast<const bf16x8*>(Kl + o + 2048u);
    };
    auto stageK = [&](int buf) {
#pragma unroll
        for (int i = 0; i < 2; ++i) {
            *reinterpret_cast<bf16x8*>(&Kst[buf][0][(t + i * 256) * 8]) = sh[i];
            *reinterpret_cast<bf16x8*>(&Kst[buf][1][(t + i * 256) * 8]) = sl[i];
        }
    };

    // mask: uniform row-base pointer + per-lane u32 offsets (row-constant)
    const u32* __restrict__ brow = bits + (((long long)b * SS + s0) << 6);
    u32 moff[2][4];
#pragma unroll
    for (int mt = 0; mt < 2; ++mt)
#pragma unroll
        for (int r = 0; r < 4; ++r)
            moff[mt][r] = (u32)((wid * 32 + mt * 16 + (lane >> 4) * 4 + r) << 6);

    loadK(0);
    stageK(0);

    float mrun[2][4], srun[2][4];
#pragma unroll
    for (int mt = 0; mt < 2; ++mt)
#pragma unroll
        for (int r = 0; r < 4; ++r) { mrun[mt][r] = -INFINITY; srun[mt][r] = 0.f; }

    const int cc0 = s0 >> 6;

    for (int cch = 0; cch < 32; ++cch) {
        const int cur = cch & 1;
        const int t0 = cch * 64;
        __syncthreads();
        if (cch + 1 < 32) loadK(cch + 1);

        uint2 mw[2][4];
        const u32 c2 = (u32)(cch * 2);
#pragma unroll
        for (int mt = 0; mt < 2; ++mt)
#pragma unroll
            for (int r = 0; r < 4; ++r)
                mw[mt][r] = *reinterpret_cast<const uint2*>(brow + moff[mt][r] + c2);

        bf16x8 kfh[4][2], kfl[4][2];
#pragma unroll
        for (int nt = 0; nt < 4; ++nt)
#pragma unroll
            for (int ks = 0; ks < 2; ++ks) {
                kfh[nt][ks] = *reinterpret_cast<const bf16x8*>(&Kst[cur][0][(nt * 2 + ks) * 512 + lane * 8]);
                kfl[nt][ks] = *reinterpret_cast<const bf16x8*>(&Kst[cur][1][(nt * 2 + ks) * 512 + lane * 8]);
            }

        f32x4 sc[2][4];
        const f32x4 zz = (f32x4){0.f, 0.f, 0.f, 0.f};
#pragma unroll
        for (int mt = 0; mt < 2; ++mt)
#pragma unroll
            for (int nt = 0; nt < 4; ++nt) {
                f32x4 a = MFMA16(qfh[mt][0], kfh[nt][0], zz);
                a = MFMA16(qfh[mt][1], kfh[nt][1], a);
                a = MFMA16(qfh[mt][0], kfl[nt][0], a);
                a = MFMA16(qfh[mt][1], kfl[nt][1], a);
                a = MFMA16(qfl[mt][0], kfh[nt][0], a);
                a = MFMA16(qfl[mt][1], kfh[nt][1], a);
                sc[mt][nt] = a;
            }

        const bool dchunk = (cch == cc0) || (cch == cc0 + 1);
#pragma unroll
        for (int mt = 0; mt < 2; ++mt)
#pragma unroll
            for (int r = 0; r < 4; ++r) {
                const u32 w0s = mw[mt][r].x >> l15;   // bit0: nt=0, bit16: nt=1
                const u32 w1s = mw[mt][r].y >> l15;   // bit0: nt=2, bit16: nt=3
                float v[4];
                v[0] = (w0s & 1u)        ? sc[mt][0][r] : NEG9;
                v[1] = (w0s & 0x10000u)  ? sc[mt][1][r] : NEG9;
                v[2] = (w1s & 1u)        ? sc[mt][2][r] : NEG9;
                v[3] = (w1s & 0x10000u)  ? sc[mt][3][r] : NEG9;
                if (dchunk) {
                    int sl_ = wid * 32 + mt * 16 + (lane >> 4) * 4 + r;
                    int cd = s0 + sl_ - t0;
#pragma unroll
                    for (int nt = 0; nt < 4; ++nt)
                        if (cd >= 0 && cd < 64 && (cd >> 4) == nt && (cd & 15) == l15)
                            sdiag[sl_] = v[nt];
                }
                float vmax = fmaxf(fmaxf(v[0], v[1]), fmaxf(v[2], v[3]));
                float mo = mrun[mt][r];
                float mn = fmaxf(mo, vmax);
                float ssum = exp2f(v[0] - mn) + exp2f(v[1] - mn) +
                             exp2f(v[2] - mn) + exp2f(v[3] - mn);
                srun[mt][r] = srun[mt][r] * exp2f(mo - mn) + ssum;
                mrun[mt][r] = mn;
            }

        if (cch + 1 < 32) stageK(cur ^ 1);
    }

#pragma unroll
    for (int mt = 0; mt < 2; ++mt)
#pragma unroll
        for (int r = 0; r < 4; ++r) {
            float mo = mrun[mt][r], so = srun[mt][r];
#pragma unroll
            for (int st = 1; st < 16; st <<= 1) {
                float m2 = __shfl_xor(mo, st, 64);
                float s2 = __shfl_xor(so, st, 64);
                float mn = fmaxf(mo, m2);
                so = so * exp2f(mo - mn) + s2 * exp2f(m2 - mn);
                mo = mn;
            }
            if (l15 == 0) {
                int sl_ = wid * 32 + mt * 16 + (lane >> 4) * 4 + r;
                dwgt[sl_] = exp2f(sdiag[sl_] - mo) / so;
            }
        }
    __syncthreads();

    const int orow = t >> 1, oc = (t & 1) * 32;
    const float w = dwgt[orow];
    const u16* vp = Vb + (bh * SS + s0 + orow) * DQQ + oc;
    float* op = out + (bh * SS + s0 + orow) * DQQ + oc;
#pragma unroll
    for (int j = 0; j < 8; ++j) {
        u32 pv = *reinterpret_cast<const u32*>(&vp[j * 4 + 0]);
        u32 pv2 = *reinterpret_cast<const u32*>(&vp[j * 4 + 2]);
        float4 o;
        o.x = lo_f(pv) * w;  o.y = hi_f(pv) * w;
        o.z = lo_f(pv2) * w; o.w = hi_f(pv2) * w;
        reinterpret_cast<float4*>(op)[j] = o;
    }
}

extern "C" void kernel_launch(void* const* d_in, const int* in_sizes, int n_in,
                              void* d_out, int out_size, void* d_ws, size_t ws_size,
                              hipStream_t stream) {
    (void)in_sizes; (void)n_in; (void)out_size; (void)ws_size;
    const float* q    = (const float*)d_in[0];
    const float* k    = (const float*)d_in[1];
    const float* v    = (const float*)d_in[2];
    const int*   mask = (const int*)d_in[3];
    const float* wq   = (const float*)d_in[4];
    const float* wk   = (const float*)d_in[5];
    const float* wv   = (const float*)d_in[6];

    const size_t NP2 = (size_t)BB * HH * SS * DQQ * 2;   // 16.78 MB per unit
    char* wsp = (char*)d_ws;
    u16* Qh = (u16*)wsp;            wsp += NP2;
    u16* Ql = (u16*)wsp;            wsp += NP2;
    u16* Kh = (u16*)wsp;            wsp += NP2;
    u16* Kl = (u16*)wsp;            wsp += NP2;
    u16* Vb = (u16*)wsp;            wsp += NP2;
    u16* Wph = (u16*)wsp;           wsp += (size_t)3 * 2048 * 512 * 2;
    u16* Wpl = (u16*)wsp;           wsp += (size_t)2 * 2048 * 512 * 2;
    u32* bits = (u32*)wsp;          wsp += (size_t)BB * SS * 64 * 4;
    u16* extra = (u16*)wsp;         // 16.78 MB slab

    // Aliased X-fragment slabs (stream-ordered hazards only)
    u16* Xh_q = Kh;    u16* Xl_q = Kl;
    u16* Xh_k = Vb;    u16* Xl_k = extra;
    u16* Xh_v = extra;

    mask_pack_k<<<dim3(2048), dim3(256), 0, stream>>>(mask, bits);
    wsplit2_k<<<dim3(512), dim3(256), 0, stream>>>(wq, Wph, Wpl, 1, SCALE_L2E);
    wsplit2_k<<<dim3(512), dim3(256), 0, stream>>>(wk, Wph + (1 << 20), Wpl + (1 << 20), 1, 1.0f);
    wsplit2_k<<<dim3(512), dim3(256), 0, stream>>>(wv, Wph + (2u << 20), Wph, 0, 1.0f);

    splitx_k<<<dim3(1024), dim3(256), 0, stream>>>(q, Xh_q, Xl_q, 1);
    proj_qk2_k<<<dim3(64, 8), dim3(256), 0, stream>>>(Xh_q, Xl_q, Wph, Wpl, Qh, Ql);

    splitx_k<<<dim3(1024), dim3(256), 0, stream>>>(k, Xh_k, Xl_k, 1);
    proj_qk2_k<<<dim3(64, 8), dim3(256), 0, stream>>>(Xh_k, Xl_k,
                                                      Wph + (1 << 20), Wpl + (1 << 20),
                                                      Kh, Kl);

    splitx_k<<<dim3(1024), dim3(256), 0, stream>>>(v, Xh_v, Xh_v, 0);
    proj_v2_k<<<dim3(64, 8), dim3(256), 0, stream>>>(Xh_v, Wph + (2u << 20), Vb);

    attn_k<<<dim3(16, 16, 4), dim3(256), 0, stream>>>(Qh, Ql, Kh, Kl, Vb, bits,
                                                      (float*)d_out);
}

// Round 9
// 335.658 us; speedup vs baseline: 1.1608x; 1.1583x over previous
//
#include <hip/hip_runtime.h>

// MultiHeadAttentionBlock: B=4,S=2048,D=1024,H=16,DQ=64
// out[b,h,s,:] = diag_softmax_weight(b,h,s) * V[b,h,s,:]   (fp32 output)
//
// Split-bf16 (hi/lo, 3-product) MFMA scores in log2 domain (SCALE*log2e in Wq).
// attn: phase A extracts the masked diag score sd per row (12 MFMA/wave),
// phase B accumulates sum = Σ 2^(v - sd) with NO max tracking (diag weight
// = 1/sum; overflow → inf → w=0, correct; all-masked → sum=2048 → 1/2048 =
// reference). exp2 is native v_exp_f32 (exp2f library call cost 40µs, r7/r8).

#define BB 4
#define SS 2048
#define DD 1024
#define HH 16
#define DQQ 64

typedef unsigned short u16;
typedef unsigned int u32;
typedef __attribute__((ext_vector_type(8))) short bf16x8;
typedef __attribute__((ext_vector_type(4))) float f32x4;

static constexpr float SCALE_L2E = 0.125f * 1.44269504f;   // folded into Wq
static constexpr float NEG9 = -1e9f;

#define MFMA16(a, b, c) __builtin_amdgcn_mfma_f32_16x16x32_bf16((a), (b), (c), 0, 0, 0)

__device__ __forceinline__ float ex2(float x) {
#if __has_builtin(__builtin_amdgcn_exp2f)
    return __builtin_amdgcn_exp2f(x);        // raw v_exp_f32 (= 2^x)
#else
    return __expf(x * 0.69314718055994531f); // fallback: native e^x path
#endif
}

__device__ __forceinline__ u16 bfrne(float x) {
    u32 u = __float_as_uint(x);
    return (u16)((u + 0x7fffu + ((u >> 16) & 1u)) >> 16);
}
__device__ __forceinline__ u32 pk2(float a, float b) {
    return (u32)bfrne(a) | ((u32)bfrne(b) << 16);
}
__device__ __forceinline__ float lo_f(u32 p) { return __uint_as_float(p << 16); }
__device__ __forceinline__ float hi_f(u32 p) { return __uint_as_float(p & 0xFFFF0000u); }

union U4V { u32 u[4]; bf16x8 v; uint4 q4; };

// ---------------- mask bit-pack ----------------
__global__ __launch_bounds__(256) void mask_pack_k(const int* __restrict__ mask,
                                                   u32* __restrict__ bits) {
    const int w = blockIdx.x * 256 + threadIdx.x;            // 0 .. B*S*64-1
    const long long row  = (long long)(w >> 6);              // b*S+s
    const long long base = row * SS + (long long)((w & 63) << 5);
    const int4* mp = reinterpret_cast<const int4*>(mask + base);
    u32 v = 0;
#pragma unroll
    for (int j = 0; j < 8; ++j) {
        int4 m4 = mp[j];
        v |= (m4.x != 0 ? 1u : 0u) << (4 * j + 0);
        v |= (m4.y != 0 ? 1u : 0u) << (4 * j + 1);
        v |= (m4.z != 0 ? 1u : 0u) << (4 * j + 2);
        v |= (m4.w != 0 ? 1u : 0u) << (4 * j + 3);
    }
    bits[w] = v;
}

// ---------------- W -> packed A-fragments (hi/lo), optional pre-scale ----------------
__global__ __launch_bounds__(256) void wsplit2_k(const float* __restrict__ W,
                                                 u16* __restrict__ Ph,
                                                 u16* __restrict__ Pl,
                                                 int has_lo, float scale) {
    const int f = blockIdx.x * 4 + (threadIdx.x >> 6);       // 0..2047
    const int lane = threadIdx.x & 63;
    const int qtile = f >> 5, kc = f & 31;
    const int h = qtile >> 2, q = ((qtile & 3) << 4) + (lane & 15);
    const int d0 = kc * 32 + (lane >> 4) * 8;
    float x[8];
#pragma unroll
    for (int j = 0; j < 8; ++j)
        x[j] = W[((long long)h * DD + d0 + j) * DQQ + q] * scale;
    U4V hh;
    hh.u[0] = pk2(x[0], x[1]); hh.u[1] = pk2(x[2], x[3]);
    hh.u[2] = pk2(x[4], x[5]); hh.u[3] = pk2(x[6], x[7]);
    const long long base = ((long long)f << 9) + lane * 8;
    *reinterpret_cast<uint4*>(Ph + base) = hh.q4;
    if (has_lo) {
        U4V ll;
        ll.u[0] = pk2(x[0] - lo_f(hh.u[0]), x[1] - hi_f(hh.u[0]));
        ll.u[1] = pk2(x[2] - lo_f(hh.u[1]), x[3] - hi_f(hh.u[1]));
        ll.u[2] = pk2(x[4] - lo_f(hh.u[2]), x[5] - hi_f(hh.u[2]));
        ll.u[3] = pk2(x[6] - lo_f(hh.u[3]), x[7] - hi_f(hh.u[3]));
        *reinterpret_cast<uint4*>(Pl + base) = ll.q4;
    }
}

// ---------------- X -> packed B-fragments (hi[/lo]), one pass ----------------
__global__ __launch_bounds__(256) void splitx_k(const float* __restrict__ X,
                                                u16* __restrict__ Xh,
                                                u16* __restrict__ Xl,
                                                int has_lo) {
    const int g = blockIdx.x * 256 + threadIdx.x;   // 0 .. 8192*32-1
    const int kc = g & 31;
    const int row = g >> 5;
    const float* xp = X + ((long long)row << 10) + kc * 32;
    const int lrow = row & 15;
    const long long base = (((long long)(row >> 4) * 32 + kc) << 9);
    float4 f[8];
#pragma unroll
    for (int i = 0; i < 8; ++i) f[i] = reinterpret_cast<const float4*>(xp)[i];
#pragma unroll
    for (int lg = 0; lg < 4; ++lg) {
        const float v0 = f[2 * lg].x, v1 = f[2 * lg].y, v2 = f[2 * lg].z, v3 = f[2 * lg].w;
        const float v4 = f[2 * lg + 1].x, v5 = f[2 * lg + 1].y,
                    v6 = f[2 * lg + 1].z, v7 = f[2 * lg + 1].w;
        U4V hh;
        hh.u[0] = pk2(v0, v1); hh.u[1] = pk2(v2, v3);
        hh.u[2] = pk2(v4, v5); hh.u[3] = pk2(v6, v7);
        const long long o = base + (lrow + 16 * lg) * 8;
        *reinterpret_cast<uint4*>(Xh + o) = hh.q4;
        if (has_lo) {
            U4V ll;
            ll.u[0] = pk2(v0 - lo_f(hh.u[0]), v1 - hi_f(hh.u[0]));
            ll.u[1] = pk2(v2 - lo_f(hh.u[1]), v3 - hi_f(hh.u[1]));
            ll.u[2] = pk2(v4 - lo_f(hh.u[2]), v5 - hi_f(hh.u[2]));
            ll.u[3] = pk2(v6 - lo_f(hh.u[3]), v7 - hi_f(hh.u[3]));
            *reinterpret_cast<uint4*>(Xl + o) = ll.q4;
        }
    }
}

// ---------------- Q/K projection (pure MFMA, packed operands) ----------------
__global__ __launch_bounds__(256) void proj_qk2_k(
        const u16* __restrict__ Xh, const u16* __restrict__ Xl,
        const u16* __restrict__ Wph, const u16* __restrict__ Wpl,
        u16* __restrict__ Oh, u16* __restrict__ Ol) {
    const int t = threadIdx.x, lane = t & 63, wid = t >> 6;
    const int lrow = lane & 15, lgrp = lane >> 4;
    const int qt0 = blockIdx.y * 8 + (wid >> 1) * 4;
    const int st0 = blockIdx.x * 8 + (wid & 1) * 4;

    f32x4 acc[4][4];
#pragma unroll
    for (int i = 0; i < 4; ++i)
#pragma unroll
        for (int j = 0; j < 4; ++j) acc[i][j] = (f32x4){0.f, 0.f, 0.f, 0.f};

#pragma unroll 2
    for (int kc = 0; kc < 32; ++kc) {
        bf16x8 Ah[4], Al[4], Bh[4], Bl[4];
#pragma unroll
        for (int mt = 0; mt < 4; ++mt) {
            const long long ab = (((long long)(qt0 + mt) * 32 + kc) << 9) + lane * 8;
            Ah[mt] = *reinterpret_cast<const bf16x8*>(Wph + ab);
            Al[mt] = *reinterpret_cast<const bf16x8*>(Wpl + ab);
        }
#pragma unroll
        for (int nt = 0; nt < 4; ++nt) {
            const long long bb = (((long long)(st0 + nt) * 32 + kc) << 9) + lane * 8;
            Bh[nt] = *reinterpret_cast<const bf16x8*>(Xh + bb);
            Bl[nt] = *reinterpret_cast<const bf16x8*>(Xl + bb);
        }
#pragma unroll
        for (int mt = 0; mt < 4; ++mt)
#pragma unroll
            for (int nt = 0; nt < 4; ++nt) {
                acc[mt][nt] = MFMA16(Ah[mt], Bh[nt], acc[mt][nt]);
                acc[mt][nt] = MFMA16(Ah[mt], Bl[nt], acc[mt][nt]);
                acc[mt][nt] = MFMA16(Al[mt], Bh[nt], acc[mt][nt]);
            }
    }

    // epilogue: 8B contiguous stores into packed fragment layout (HW-verified)
#pragma unroll
    for (int mt = 0; mt < 4; ++mt) {
        const int qtg = qt0 + mt;
        const int hh_ = qtg >> 2;
        const int qb = ((qtg & 3) << 4) + (lgrp << 2);     // q of r=0
#pragma unroll
        for (int nt = 0; nt < 4; ++nt) {
            const int c = (st0 + nt) * 16 + lrow;
            const int b = c >> 11, s = c & 2047;
            const int bh = (b << 4) + hh_;
            const float x0 = acc[mt][nt][0], x1 = acc[mt][nt][1],
                        x2 = acc[mt][nt][2], x3 = acc[mt][nt][3];
            const u32 h01 = pk2(x0, x1), h23 = pk2(x2, x3);
            const u32 l01 = pk2(x0 - lo_f(h01), x1 - hi_f(h01));
            const u32 l23 = pk2(x2 - lo_f(h23), x3 - hi_f(h23));
            const int st = s >> 4, kcq = qb >> 5;
            const int lanep = lrow + (((qb & 31) >> 3) << 4);
            const long long oi = ((((long long)bh * 128 + st) * 2 + kcq) << 9)
                                 + lanep * 8 + (qb & 7);
            *reinterpret_cast<uint2*>(Oh + oi) = make_uint2(h01, h23);
            *reinterpret_cast<uint2*>(Ol + oi) = make_uint2(l01, l23);
        }
    }
}

// ---------------- V projection (pure MFMA, bf16, row-major out) ----------------
__global__ __launch_bounds__(256) void proj_v2_k(
        const u16* __restrict__ Xh, const u16* __restrict__ Wph,
        u16* __restrict__ Vb) {
    const int t = threadIdx.x, lane = t & 63, wid = t >> 6;
    const int lrow = lane & 15, lgrp = lane >> 4;
    const int qt0 = blockIdx.y * 8 + (wid >> 1) * 4;
    const int st0 = blockIdx.x * 8 + (wid & 1) * 4;

    f32x4 acc[4][4];
#pragma unroll
    for (int i = 0; i < 4; ++i)
#pragma unroll
        for (int j = 0; j < 4; ++j) acc[i][j] = (f32x4){0.f, 0.f, 0.f, 0.f};

#pragma unroll 2
    for (int kc = 0; kc < 32; ++kc) {
        bf16x8 Ah[4], Bh[4];
#pragma unroll
        for (int mt = 0; mt < 4; ++mt) {
            const long long ab = (((long long)(qt0 + mt) * 32 + kc) << 9) + lane * 8;
            Ah[mt] = *reinterpret_cast<const bf16x8*>(Wph + ab);
        }
#pragma unroll
        for (int nt = 0; nt < 4; ++nt) {
            const long long bb = (((long long)(st0 + nt) * 32 + kc) << 9) + lane * 8;
            Bh[nt] = *reinterpret_cast<const bf16x8*>(Xh + bb);
        }
#pragma unroll
        for (int mt = 0; mt < 4; ++mt)
#pragma unroll
            for (int nt = 0; nt < 4; ++nt)
                acc[mt][nt] = MFMA16(Ah[mt], Bh[nt], acc[mt][nt]);
    }

#pragma unroll
    for (int mt = 0; mt < 4; ++mt) {
        const int qtg = qt0 + mt;
        const int hh_ = qtg >> 2;
        const int qb = ((qtg & 3) << 4) + (lgrp << 2);
#pragma unroll
        for (int nt = 0; nt < 4; ++nt) {
            const int c = (st0 + nt) * 16 + lrow;
            const int b = c >> 11, s = c & 2047;
            const int bh = (b << 4) + hh_;
            const u32 h01 = pk2(acc[mt][nt][0], acc[mt][nt][1]);
            const u32 h23 = pk2(acc[mt][nt][2], acc[mt][nt][3]);
            const long long oi = ((long long)bh * SS + s) * DQQ + qb;
            *reinterpret_cast<uint2*>(Vb + oi) = make_uint2(h01, h23);
        }
    }
}

// ---------------- fused scores + diag-reference softmax + output ----------------
__global__ __launch_bounds__(256) void attn_k(
        const u16* __restrict__ Qh, const u16* __restrict__ Ql,
        const u16* __restrict__ Kh, const u16* __restrict__ Kl,
        const u16* __restrict__ Vb, const u32* __restrict__ bits,
        float* __restrict__ out) {
    const int qt = blockIdx.x, h = blockIdx.y, b = blockIdx.z;
    const int s0 = qt * 128;
    const long long bh = b * HH + h;
    const int t = threadIdx.x, lane = t & 63, wid = t >> 6;
    const int l15 = lane & 15, lgrp = lane >> 4;

    __shared__ u16 Kst[2][2][4096];
    __shared__ float sdiag[128];
    __shared__ float dwgt[128];

    // Q fragments (packed layout)
    bf16x8 qfh[2][2], qfl[2][2];
#pragma unroll
    for (int mt = 0; mt < 2; ++mt)
#pragma unroll
        for (int ks = 0; ks < 2; ++ks) {
            const int stq = qt * 8 + wid * 2 + mt;
            const long long gi = (((bh * 128 + stq) * 2 + ks) << 9) + lane * 8;
            qfh[mt][ks] = *reinterpret_cast<const bf16x8*>(&Qh[gi]);
            qfl[mt][ks] = *reinterpret_cast<const bf16x8*>(&Ql[gi]);
        }

    const u32 kbase = (u32)(bh * 131072u) + (u32)t * 8u;
    bf16x8 sh[2], sl[2];
    auto loadK = [&](int cchN) {
        const u32 o = kbase + (u32)cchN * 4096u;
        sh[0] = *reinterpret_cast<const bf16x8*>(Kh + o);
        sl[0] = *reinterpret_cast<const bf16x8*>(Kl + o);
        sh[1] = *reinterpret_cast<const bf16x8*>(Kh + o + 2048u);
        sl[1] = *reinterpret_cast<const bf16x8*>(Kl + o + 2048u);
    };
    auto stageK = [&](int buf) {
#pragma unroll
        for (int i = 0; i < 2; ++i) {
            *reinterpret_cast<bf16x8*>(&Kst[buf][0][(t + i * 256) * 8]) = sh[i];
            *reinterpret_cast<bf16x8*>(&Kst[buf][1][(t + i * 256) * 8]) = sl[i];
        }
    };

    const u32* __restrict__ brow = bits + (((long long)b * SS + s0) << 6);
    u32 moff[2][4];
#pragma unroll
    for (int mt = 0; mt < 2; ++mt)
#pragma unroll
        for (int r = 0; r < 4; ++r)
            moff[mt][r] = (u32)((wid * 32 + mt * 16 + lgrp * 4 + r) << 6);

    const f32x4 zz = (f32x4){0.f, 0.f, 0.f, 0.f};

    // ---------- Phase A: diag score extraction ----------
    loadK(2 * qt);     stageK(0);
    loadK(2 * qt + 1); stageK(1);
    __syncthreads();
    {
        const int bufA = wid >> 1;          // which diag chunk this wave's rows use
        const int nt0 = (wid & 1) * 2;      // diag tiles nt0+mt
        const int cA = 2 * qt + bufA;
#pragma unroll
        for (int mt = 0; mt < 2; ++mt) {
            const int ntd = nt0 + mt;
            bf16x8 kh0 = *reinterpret_cast<const bf16x8*>(&Kst[bufA][0][(ntd * 2 + 0) * 512 + lane * 8]);
            bf16x8 kh1 = *reinterpret_cast<const bf16x8*>(&Kst[bufA][0][(ntd * 2 + 1) * 512 + lane * 8]);
            bf16x8 kl0 = *reinterpret_cast<const bf16x8*>(&Kst[bufA][1][(ntd * 2 + 0) * 512 + lane * 8]);
            bf16x8 kl1 = *reinterpret_cast<const bf16x8*>(&Kst[bufA][1][(ntd * 2 + 1) * 512 + lane * 8]);
            f32x4 a = MFMA16(qfh[mt][0], kh0, zz);
            a = MFMA16(qfh[mt][1], kh1, a);
            a = MFMA16(qfh[mt][0], kl0, a);
            a = MFMA16(qfh[mt][1], kl1, a);
            a = MFMA16(qfl[mt][0], kh0, a);
            a = MFMA16(qfl[mt][1], kh1, a);
#pragma unroll
            for (int r = 0; r < 4; ++r) {
                if (l15 == lgrp * 4 + r) {      // this lane holds row's diag
                    const u32 word = brow[moff[mt][r] + (u32)(cA * 2) + (u32)(ntd >> 1)];
                    const u32 bit = (word >> ((ntd & 1) * 16 + l15)) & 1u;
                    sdiag[wid * 32 + mt * 16 + lgrp * 4 + r] = bit ? a[r] : NEG9;
                }
            }
        }
    }
    __syncthreads();

    float sdA[2][4], nsd[2][4];
#pragma unroll
    for (int mt = 0; mt < 2; ++mt) {
        float4 v4 = *reinterpret_cast<const float4*>(&sdiag[wid * 32 + mt * 16 + lgrp * 4]);
        sdA[mt][0] = v4.x; sdA[mt][1] = v4.y; sdA[mt][2] = v4.z; sdA[mt][3] = v4.w;
#pragma unroll
        for (int r = 0; r < 4; ++r) nsd[mt][r] = NEG9 - sdA[mt][r];
    }

    // ---------- Phase B: accumulate sum = Σ 2^(v - sd) ----------
    loadK(0); stageK(0);
    float srun[2][4];
#pragma unroll
    for (int mt = 0; mt < 2; ++mt)
#pragma unroll
        for (int r = 0; r < 4; ++r) srun[mt][r] = 0.f;

    for (int cch = 0; cch < 32; ++cch) {
        const int cur = cch & 1;
        __syncthreads();
        if (cch + 1 < 32) loadK(cch + 1);

        uint2 mw[2][4];
        const u32 c2 = (u32)(cch * 2);
#pragma unroll
        for (int mt = 0; mt < 2; ++mt)
#pragma unroll
            for (int r = 0; r < 4; ++r)
                mw[mt][r] = *reinterpret_cast<const uint2*>(brow + moff[mt][r] + c2);

        bf16x8 kfh[4][2], kfl[4][2];
#pragma unroll
        for (int nt = 0; nt < 4; ++nt)
#pragma unroll
            for (int ks = 0; ks < 2; ++ks) {
                kfh[nt][ks] = *reinterpret_cast<const bf16x8*>(&Kst[cur][0][(nt * 2 + ks) * 512 + lane * 8]);
                kfl[nt][ks] = *reinterpret_cast<const bf16x8*>(&Kst[cur][1][(nt * 2 + ks) * 512 + lane * 8]);
            }

        f32x4 sc[2][4];
#pragma unroll
        for (int mt = 0; mt < 2; ++mt)
#pragma unroll
            for (int nt = 0; nt < 4; ++nt) {
                f32x4 a = MFMA16(qfh[mt][0], kfh[nt][0], zz);
                a = MFMA16(qfh[mt][1], kfh[nt][1], a);
                a = MFMA16(qfh[mt][0], kfl[nt][0], a);
                a = MFMA16(qfh[mt][1], kfl[nt][1], a);
                a = MFMA16(qfl[mt][0], kfh[nt][0], a);
                a = MFMA16(qfl[mt][1], kfh[nt][1], a);
                sc[mt][nt] = a;
            }

#pragma unroll
        for (int mt = 0; mt < 2; ++mt)
#pragma unroll
            for (int r = 0; r < 4; ++r) {
                const u32 w0s = mw[mt][r].x >> l15;
                const u32 w1s = mw[mt][r].y >> l15;
                const float sd = sdA[mt][r], nd = nsd[mt][r];
                float d0 = sc[mt][0][r] - sd;
                float d1 = sc[mt][1][r] - sd;
                float d2 = sc[mt][2][r] - sd;
                float d3 = sc[mt][3][r] - sd;
                d0 = (w0s & 1u)       ? d0 : nd;
                d1 = (w0s & 0x10000u) ? d1 : nd;
                d2 = (w1s & 1u)       ? d2 : nd;
                d3 = (w1s & 0x10000u) ? d3 : nd;
                srun[mt][r] += (ex2(d0) + ex2(d1)) + (ex2(d2) + ex2(d3));
            }

        if (cch + 1 < 32) stageK(cur ^ 1);
    }

    // reduce across the 16 lanes of each row group; w = 1/sum
#pragma unroll
    for (int mt = 0; mt < 2; ++mt)
#pragma unroll
        for (int r = 0; r < 4; ++r) {
            float so = srun[mt][r];
#pragma unroll
            for (int st = 1; st < 16; st <<= 1)
                so += __shfl_xor(so, st, 64);
            if (l15 == 0)
                dwgt[wid * 32 + mt * 16 + lgrp * 4 + r] = 1.0f / so;
        }
    __syncthreads();

    const int orow = t >> 1, oc = (t & 1) * 32;
    const float w = dwgt[orow];
    const u16* vp = Vb + (bh * SS + s0 + orow) * DQQ + oc;
    float* op = out + (bh * SS + s0 + orow) * DQQ + oc;
#pragma unroll
    for (int j = 0; j < 8; ++j) {
        u32 pv = *reinterpret_cast<const u32*>(&vp[j * 4 + 0]);
        u32 pv2 = *reinterpret_cast<const u32*>(&vp[j * 4 + 2]);
        float4 o;
        o.x = lo_f(pv) * w;  o.y = hi_f(pv) * w;
        o.z = lo_f(pv2) * w; o.w = hi_f(pv2) * w;
        reinterpret_cast<float4*>(op)[j] = o;
    }
}

extern "C" void kernel_launch(void* const* d_in, const int* in_sizes, int n_in,
                              void* d_out, int out_size, void* d_ws, size_t ws_size,
                              hipStream_t stream) {
    (void)in_sizes; (void)n_in; (void)out_size; (void)ws_size;
    const float* q    = (const float*)d_in[0];
    const float* k    = (const float*)d_in[1];
    const float* v    = (const float*)d_in[2];
    const int*   mask = (const int*)d_in[3];
    const float* wq   = (const float*)d_in[4];
    const float* wk   = (const float*)d_in[5];
    const float* wv   = (const float*)d_in[6];

    const size_t NP2 = (size_t)BB * HH * SS * DQQ * 2;   // 16.78 MB per unit
    char* wsp = (char*)d_ws;
    u16* Qh = (u16*)wsp;            wsp += NP2;
    u16* Ql = (u16*)wsp;            wsp += NP2;
    u16* Kh = (u16*)wsp;            wsp += NP2;
    u16* Kl = (u16*)wsp;            wsp += NP2;
    u16* Vb = (u16*)wsp;            wsp += NP2;
    u16* Wph = (u16*)wsp;           wsp += (size_t)3 * 2048 * 512 * 2;
    u16* Wpl = (u16*)wsp;           wsp += (size_t)2 * 2048 * 512 * 2;
    u32* bits = (u32*)wsp;          wsp += (size_t)BB * SS * 64 * 4;
    u16* extra = (u16*)wsp;         // 16.78 MB slab

    // Aliased X-fragment slabs (stream-ordered hazards only)
    u16* Xh_q = Kh;    u16* Xl_q = Kl;
    u16* Xh_k = Vb;    u16* Xl_k = extra;
    u16* Xh_v = extra;

    mask_pack_k<<<dim3(2048), dim3(256), 0, stream>>>(mask, bits);
    wsplit2_k<<<dim3(512), dim3(256), 0, stream>>>(wq, Wph, Wpl, 1, SCALE_L2E);
    wsplit2_k<<<dim3(512), dim3(256), 0, stream>>>(wk, Wph + (1 << 20), Wpl + (1 << 20), 1, 1.0f);
    wsplit2_k<<<dim3(512), dim3(256), 0, stream>>>(wv, Wph + (2u << 20), Wph, 0, 1.0f);

    splitx_k<<<dim3(1024), dim3(256), 0, stream>>>(q, Xh_q, Xl_q, 1);
    proj_qk2_k<<<dim3(64, 8), dim3(256), 0, stream>>>(Xh_q, Xl_q, Wph, Wpl, Qh, Ql);

    splitx_k<<<dim3(1024), dim3(256), 0, stream>>>(k, Xh_k, Xl_k, 1);
    proj_qk2_k<<<dim3(64, 8), dim3(256), 0, stream>>>(Xh_k, Xl_k,
                                                      Wph + (1 << 20), Wpl + (1 << 20),
                                                      Kh, Kl);

    splitx_k<<<dim3(1024), dim3(256), 0, stream>>>(v, Xh_v, Xh_v, 0);
    proj_v2_k<<<dim3(64, 8), dim3(256), 0, stream>>>(Xh_v, Wph + (2u << 20), Vb);

    attn_k<<<dim3(16, 16, 4), dim3(256), 0, stream>>>(Qh, Ql, Kh, Kl, Vb, bits,
                                                      (float*)d_out);
}